// Round 1
// 337.752 us; speedup vs baseline: 1.0606x; 1.0606x over previous
//
#include <hip/hip_runtime.h>

#define CIN   256
#define COUT  256
#define HH    56
#define WW    56
#define BATCH 32
#define KTOT  2304           // CIN * 9, ordered (kh,kw,ci)
#define HP    58
#define WP    58
#define NPIX  (BATCH*HH*WW)  // 100352
#define HWSZ  (HH*WW)        // 3136

typedef __bf16 bf16x8 __attribute__((ext_vector_type(8)));
typedef float  f32x4  __attribute__((ext_vector_type(4)));

#define AS1 __attribute__((address_space(1)))
#define AS3 __attribute__((address_space(3)))

__device__ __forceinline__ unsigned short f2bf(float f) {
  union { float f; unsigned int u; } v; v.f = f;
  unsigned int u = v.u;
  u += 0x7fffu + ((u >> 16) & 1u);   // round-to-nearest-even
  return (unsigned short)(u >> 16);
}

__device__ __forceinline__ void async16(const void* g, void* l) {
  __builtin_amdgcn_global_load_lds((const AS1 unsigned int*)g,
                                   (AS3 unsigned int*)l, 16, 0, 0);
}

// ---- kernel 1: ternary-quantize weights, reorder OIHW -> [co][kh][kw][ci] bf16
__global__ __launch_bounds__(256) void quant_w(const float* __restrict__ w,
                                               unsigned short* __restrict__ wr) {
  int tid = blockIdx.x * 256 + threadIdx.x;
  if (tid >= COUT * KTOT) return;
  int co  = tid / KTOT;
  int rem = tid - co * KTOT;
  int tap = rem >> 8;          // kh*3+kw
  int ci  = rem & 255;
  int kh  = tap / 3;
  int kw  = tap - kh * 3;
  float v = w[((co * CIN + ci) * 3 + kh) * 3 + kw];
  float q = (fabsf(v) > 0.05f) ? ((v > 0.f) ? 1.f : -1.f) : 0.f;
  wr[tid] = f2bf(q);           // -1/0/+1 exact in bf16
}

// ---- kernel 2: x NCHW fp32 -> zero-padded NHWC bf16  Xp[n][hp][wp][ci]
__global__ __launch_bounds__(256) void pad_nhwc(const float* __restrict__ x,
                                                unsigned short* __restrict__ xp) {
  const int nhp = blockIdx.x;            // n*58 + hp
  const int n   = nhp / HP;
  const int hp  = nhp - n * HP;
  const int ci0 = blockIdx.y * 64;
  const int t   = threadIdx.x;
  const size_t obase = (size_t)nhp * (WP * 256);

  __shared__ __align__(16) float tile[64 * 56];
  const bool hborder = (hp == 0) || (hp == HP - 1);

  if (!hborder) {
    const int h = hp - 1;
    // 64 channels x 14 float4 = 896 vector loads (was 3584 scalar dwords)
    #pragma unroll
    for (int it = 0; it < 4; ++it) {
      int linear = it * 256 + t;
      if (linear < 896) {
        int cil = linear / 14;
        int w4  = linear - cil * 14;
        *(float4*)&tile[cil * 56 + w4 * 4] =
            *(const float4*)&x[(((size_t)(n * CIN + ci0 + cil)) * HH + h) * WW + w4 * 4];
      }
    }
  }
  __syncthreads();

  #pragma unroll
  for (int it = 0; it < 2; ++it) {               // 58*8 = 464 16B-chunks
    int linear = it * 256 + t;
    if (linear < 464) {
      int wp = linear >> 3;
      int g  = linear & 7;                       // ci group of 8
      unsigned int pk[4] = {0u, 0u, 0u, 0u};
      if (!hborder && wp != 0 && wp != WP - 1) {
        #pragma unroll
        for (int j = 0; j < 4; ++j) {
          unsigned int lo = f2bf(tile[(g * 8 + 2 * j) * 56 + (wp - 1)]);
          unsigned int hi = f2bf(tile[(g * 8 + 2 * j + 1) * 56 + (wp - 1)]);
          pk[j] = lo | (hi << 16);
        }
      }
      uint4 v; v.x = pk[0]; v.y = pk[1]; v.z = pk[2]; v.w = pk[3];
      *(uint4*)(xp + obase + (size_t)wp * 256 + ci0 + g * 8) = v;
    }
  }
}

// ---- kernel 3: implicit GEMM  C[co][p] = sum_k Wr[co][k] * Xcol[k][p]
// 128x128 tile, BK=32, 4 waves (2x2), each wave 4x4 of mfma 16x16x32 bf16
// This round: (a) bijective XCD swizzle so each XCD owns a contiguous 98-p-block
// chunk (co-pair adjacent -> shared B panel in one L2); (b) 2-phase double-
// buffered prefetch (T3-minimum): stage k+1 before computing k, ONE barrier/step.
__global__ __launch_bounds__(256, 2) void conv_gemm(
    const unsigned short* __restrict__ Wr,
    const unsigned short* __restrict__ Xp,
    const float* __restrict__ bias,
    float* __restrict__ out) {
  __shared__ __align__(16) unsigned short a_tile[2][128 * 32];  // [co][k] 8 KB x2
  __shared__ __align__(16) unsigned short b_tile[2][128 * 32];  // [p][k]  8 KB x2

  const int t    = threadIdx.x;
  const int lane = t & 63;
  const int wv   = t >> 6;
  const int wm   = wv >> 1;       // wave row (co)
  const int wn   = wv & 1;        // wave col (pixel)
  const int l15  = lane & 15;
  const int quad = lane >> 4;

  // ---- XCD-aware bijective swizzle over the flat 1568-block grid.
  // 1568 = 8 XCDs * 196; nf enumerates (pb,cob) with co-pairs adjacent so both
  // co-blocks of a pixel panel land on the same XCD back-to-back.
  const int f   = blockIdx.x;
  const int xcd = f & 7;
  const int pos = f >> 3;
  const int nf  = xcd * 196 + pos;
  const int cob = nf & 1;
  const int pb  = nf >> 1;        // [0,784): contiguous 98-block chunk per XCD

  const int co0 = cob * 128;
  const int p0  = pb * 128;

  // staging: thread t stages 16B chunk (row = t/4, kchunk = t%4) twice (rows +0,+64)
  const int srow = t >> 2;
  const int scol = t & 3;

  const size_t aIdx0 = (size_t)(co0 + srow) * KTOT + scol * 8;
  const size_t aIdx1 = aIdx0 + (size_t)64 * KTOT;

  const int pA = p0 + srow;
  const int pB = pA + 64;
  const int nA = pA / HWSZ;  const int hwA = pA - nA * HWSZ;
  const int hA = hwA / WW;   const int wA  = hwA - hA * WW;
  const int nB = pB / HWSZ;  const int hwB = pB - nB * HWSZ;
  const int hB = hwB / WW;   const int wB  = hwB - hB * WW;
  const size_t bIdx0 = ((size_t)((nA * HP + hA) * WP + wA)) * 256 + scol * 8;
  const size_t bIdx1 = ((size_t)((nB * HP + hB) * WP + wB)) * 256 + scol * 8;

  auto stage = [&](int kk, int s) {
    const int tap   = kk >> 3;            // ci block of 32 never straddles a tap
    const int cio   = (kk & 7) << 5;
    const int kh    = tap / 3;
    const int kw    = tap - kh * 3;
    const int koffW = kk << 5;
    const int koffX = (kh * WP + kw) * 256 + cio;
    async16(Wr + koffW + aIdx0, &a_tile[s][0] + t * 8);
    async16(Wr + koffW + aIdx1, &a_tile[s][0] + 2048 + t * 8);
    async16(Xp + koffX + bIdx0, &b_tile[s][0] + t * 8);
    async16(Xp + koffX + bIdx1, &b_tile[s][0] + 2048 + t * 8);
  };

  f32x4 acc[4][4];
  #pragma unroll
  for (int i = 0; i < 4; ++i)
    #pragma unroll
    for (int j = 0; j < 4; ++j)
      acc[i][j] = (f32x4){0.f, 0.f, 0.f, 0.f};

  // prologue: fill buffer 0
  stage(0, 0);
  __syncthreads();                 // compiler drains vmcnt(0) before s_barrier

  for (int kk = 0; kk < KTOT / 32; ++kk) {
    const int cur = kk & 1;
    if (kk < KTOT / 32 - 1)
      stage(kk + 1, cur ^ 1);      // prefetch flies under ds_read + MFMA below

    bf16x8 af[4], bfr[4];
    #pragma unroll
    for (int mt = 0; mt < 4; ++mt)
      af[mt] = *(const bf16x8*)(&a_tile[cur][0] +
                                ((wm * 64 + mt * 16 + l15) * 32 + quad * 8));
    #pragma unroll
    for (int nt = 0; nt < 4; ++nt)
      bfr[nt] = *(const bf16x8*)(&b_tile[cur][0] +
                                 ((wn * 64 + nt * 16 + l15) * 32 + quad * 8));

    #pragma unroll
    for (int mt = 0; mt < 4; ++mt)
      #pragma unroll
      for (int nt = 0; nt < 4; ++nt)
        acc[mt][nt] = __builtin_amdgcn_mfma_f32_16x16x32_bf16(
            af[mt], bfr[nt], acc[mt][nt], 0, 0, 0);

    __syncthreads();               // one barrier/step: drains prefetch vmcnt,
                                   // orders this step's ds_reads before overwrite
  }

  // epilogue: C/D layout col = lane&15 (pixel), row = quad*4+reg (co)
  float bv[4][4];
  #pragma unroll
  for (int mt = 0; mt < 4; ++mt)
    #pragma unroll
    for (int r = 0; r < 4; ++r)
      bv[mt][r] = bias[co0 + wm * 64 + mt * 16 + quad * 4 + r];

  #pragma unroll
  for (int nt = 0; nt < 4; ++nt) {
    const int p  = p0 + wn * 64 + nt * 16 + l15;
    const int np = p / HWSZ;
    const int hw = p - np * HWSZ;
    const size_t obase = (size_t)np * (COUT * HWSZ) + hw;
    #pragma unroll
    for (int mt = 0; mt < 4; ++mt) {
      const int co = co0 + wm * 64 + mt * 16 + quad * 4;
      #pragma unroll
      for (int r = 0; r < 4; ++r)
        out[obase + (size_t)(co + r) * HWSZ] = acc[mt][nt][r] + bv[mt][r];
    }
  }
}

extern "C" void kernel_launch(void* const* d_in, const int* in_sizes, int n_in,
                              void* d_out, int out_size, void* d_ws, size_t ws_size,
                              hipStream_t stream) {
  const float* x    = (const float*)d_in[0];
  const float* w    = (const float*)d_in[1];
  const float* bias = (const float*)d_in[2];
  float* out        = (float*)d_out;

  // workspace layout: Xp (padded NHWC bf16) then Wr (reordered ternary bf16)
  unsigned short* xp = (unsigned short*)d_ws;                       // 55,115,776 B
  unsigned short* wr = (unsigned short*)((char*)d_ws + 55115776);   //  1,179,648 B

  quant_w<<<dim3((COUT * KTOT) / 256), dim3(256), 0, stream>>>(w, wr);
  pad_nhwc<<<dim3(BATCH * HP, 4), dim3(256), 0, stream>>>(x, xp);
  conv_gemm<<<dim3(NPIX / 128 * 2), dim3(256), 0, stream>>>(wr, xp, bias, out);
}